// Round 15
// baseline (1188.432 us; speedup 1.0000x reference)
//
#include <hip/hip_runtime.h>
#include <math.h>

#define BB 8
#define TT 4095
#define DD 1024
#define NN 7
#define GG 585           // TT / NN
#define BN (BB * NN)     // 56
#define GD 4             // gemv1: output columns per producer block
#define GD2 4            // attn+gemv2: output columns per consumer block
#define NB1 (DD / GD)    // 256 producer blocks
#define NB2 (DD / GD2)   // 256 consumer blocks
#define KS 8             // k_mean: k-slices of 32 float4 (512 B)

typedef float nfloat4 __attribute__((ext_vector_type(4)));

// ---------------------------------------------------------------------------
// K1: fused group-mean.  grid = (KS=8, BN), block = 512.  [R14 exact]
// Block (0,0) thread 0 also zeroes the k_mid handshake counter.
// ---------------------------------------------------------------------------
__global__ __launch_bounds__(512) void k_mean(
    const float* __restrict__ x, float* __restrict__ nodes,
    unsigned* __restrict__ done) {
    if (blockIdx.x == 0 && blockIdx.y == 0 && threadIdx.x == 0) *done = 0u;

    int ks = blockIdx.x;             // 0..7 (32-float4 slice of D)
    int bn = blockIdx.y;             // 0..55
    int b = bn / NN, n = bn % NN;
    int t = threadIdx.x;
    int gi = t >> 5;                 // 0..15 g-partition
    int kg = t & 31;                 // 0..31 f4 within slice

    const float4* xp = (const float4*)(x + (size_t)(b * TT + n) * DD) +
                       ks * 32 + kg;
    float ax = 0.f, ay = 0.f, az = 0.f, aw = 0.f;
    #pragma unroll 4
    for (int g = gi; g < GG; g += 16) {
        float4 v = xp[(size_t)g * NN * (DD / 4)];
        ax += v.x; ay += v.y; az += v.z; aw += v.w;
    }

    __shared__ float4 red[16][32];   // [gi][kg], 8 KB
    float4 r; r.x = ax; r.y = ay; r.z = az; r.w = aw;
    red[gi][kg] = r;
    __syncthreads();

    if (t < 32) {                    // kg = t
        float4 a = red[0][t];
        #pragma unroll
        for (int g2 = 1; g2 < 16; ++g2) {
            float4 v = red[g2][t];
            a.x += v.x; a.y += v.y; a.z += v.z; a.w += v.w;
        }
        const float sc = 1.0f / (float)GG;
        a.x *= sc; a.y *= sc; a.z *= sc; a.w *= sc;
        ((float4*)(nodes + (size_t)bn * DD))[ks * 32 + t] = a;
    }
}

// ---------------------------------------------------------------------------
// K2: merged middle kernel.  grid = NB1 + NB2 = 512, block = 512.
// Blocks [0, NB1): gemv_f producer (h, fpart), then release-add `done`.
// Blocks [NB1, 512): spin-wait (acquire) until done == NB1, then attn+gemv2.
// __launch_bounds__(512,4): VGPR<=128 -> >=2 blocks/CU -> all 512 co-resident
// regardless of dispatch order (no deadlock).  Cross-XCD visibility via
// agent-scope release/acquire (fence + L2 writeback / invalidate).
// ---------------------------------------------------------------------------
__global__ __launch_bounds__(512, 4) void k_mid(
    const float* __restrict__ A, const float* __restrict__ Wm1,
    const float* __restrict__ a_w, const float* __restrict__ Wm2,
    float* __restrict__ h, float* __restrict__ fpart,
    float* __restrict__ on, unsigned* __restrict__ done) {
    int t = threadIdx.x;
    int wave = t >> 6, lane = t & 63;

    if (blockIdx.x < NB1) {
        // ---------------- producer: h = A @ Wm1^T + f-partials ----------------
        int d0 = blockIdx.x * GD;

        float4 wv[GD][4];
        #pragma unroll
        for (int dd = 0; dd < GD; ++dd) {
            const float4* wp = (const float4*)(Wm1 + (size_t)(d0 + dd) * DD);
            #pragma unroll
            for (int kk = 0; kk < 4; ++kk) wv[dd][kk] = wp[lane + 64 * kk];
        }

        const float4* ap = (const float4*)A + (size_t)(wave * 7) * (DD / 4);
        float acc[7][GD];
        #pragma unroll
        for (int i = 0; i < 7; ++i) {
            const float4* ar = ap + (size_t)i * (DD / 4);
            float4 a0 = ar[lane];
            float4 a1 = ar[lane + 64];
            float4 a2 = ar[lane + 128];
            float4 a3 = ar[lane + 192];
            #pragma unroll
            for (int dd = 0; dd < GD; ++dd) {
                float v = a0.x * wv[dd][0].x + a0.y * wv[dd][0].y +
                          a0.z * wv[dd][0].z + a0.w * wv[dd][0].w;
                v += a1.x * wv[dd][1].x + a1.y * wv[dd][1].y +
                     a1.z * wv[dd][1].z + a1.w * wv[dd][1].w;
                v += a2.x * wv[dd][2].x + a2.y * wv[dd][2].y +
                     a2.z * wv[dd][2].z + a2.w * wv[dd][2].w;
                v += a3.x * wv[dd][3].x + a3.y * wv[dd][3].y +
                     a3.z * wv[dd][3].z + a3.w * wv[dd][3].w;
                acc[i][dd] = v;
            }
        }

        float a1v[GD], a2v[GD];
        #pragma unroll
        for (int dd = 0; dd < GD; ++dd) {
            a1v[dd] = a_w[d0 + dd];
            a2v[dd] = a_w[DD + d0 + dd];
        }

        #pragma unroll
        for (int i = 0; i < 7; ++i) {
            float f1i = 0.f, f2i = 0.f;
            #pragma unroll
            for (int dd = 0; dd < GD; ++dd) {
                float v = acc[i][dd];
                v += __shfl_xor(v, 1, 64);
                v += __shfl_xor(v, 2, 64);
                v += __shfl_xor(v, 4, 64);
                v += __shfl_xor(v, 8, 64);
                v += __shfl_xor(v, 16, 64);
                v += __shfl_xor(v, 32, 64);
                f1i += v * a1v[dd];
                f2i += v * a2v[dd];
                if (lane == 0) h[(size_t)(wave * 7 + i) * DD + d0 + dd] = v;
            }
            if (lane == 0) {
                int row = wave * 7 + i;
                fpart[(size_t)blockIdx.x * BN + row] = f1i;
                fpart[(size_t)(NB1 + blockIdx.x) * BN + row] = f2i;
            }
        }

        __syncthreads();             // all block stores at least in L2
        if (t == 0) {
            __threadfence();         // agent fence: L2 writeback
            __hip_atomic_fetch_add(done, 1u, __ATOMIC_RELEASE,
                                   __HIP_MEMORY_SCOPE_AGENT);
        }
    } else {
        // ---------------- consumer: attention + on = s @ Wm2^T ----------------
        int d0 = (blockIdx.x - NB1) * GD2;

        // bounded spin: producers finish in ~5 us; bound ~0.5 s converts any
        // handshake bug into a clean validation failure instead of a hang.
        long it = 0;
        while (__hip_atomic_load(done, __ATOMIC_ACQUIRE,
                                 __HIP_MEMORY_SCOPE_AGENT) < (unsigned)NB1) {
            __builtin_amdgcn_s_sleep(2);
            if (++it > (1L << 22)) break;
        }

        __shared__ float f[2][BN];
        __shared__ float alC[8][NN][NN];

        if (t < 2 * BN) {
            int sel = t / BN, row = t - sel * BN;
            const float* fp = fpart + (size_t)sel * NB1 * BN + row;
            float s0 = 0.f, s1 = 0.f, s2 = 0.f, s3 = 0.f;
            #pragma unroll 4
            for (int blk = 0; blk < NB1; blk += 4) {
                s0 += fp[(size_t)blk * BN];
                s1 += fp[(size_t)(blk + 1) * BN];
                s2 += fp[(size_t)(blk + 2) * BN];
                s3 += fp[(size_t)(blk + 3) * BN];
            }
            f[sel][row] = (s0 + s1) + (s2 + s3);
        }
        __syncthreads();

        int b = wave;                // one batch per wave
        if (lane < NN) {
            int i = lane;
            unsigned m = (i == 0) ? 0x7Eu
                : (1u | (1u << (i % 6 + 1)) | (1u << ((i + 4) % 6 + 1)));
            float f1 = f[0][b * NN + i];
            float mx = -1e30f;
            #pragma unroll
            for (int j = 0; j < NN; ++j)
                if ((m >> j) & 1u) mx = fmaxf(mx, f1 + f[1][b * NN + j]);
            float ssum = 0.f;
            float ex[NN];
            #pragma unroll
            for (int j = 0; j < NN; ++j) {
                ex[j] = ((m >> j) & 1u) ? __expf(f1 + f[1][b * NN + j] - mx) : 0.f;
                ssum += ex[j];
            }
            float inv = 1.0f / ssum;
            #pragma unroll
            for (int j = 0; j < NN; ++j) alC[wave][i][j] = ex[j] * inv;
        }
        __syncthreads();

        float acc[NN][GD2];
        #pragma unroll
        for (int i = 0; i < NN; ++i)
            #pragma unroll
            for (int dd = 0; dd < GD2; ++dd) acc[i][dd] = 0.f;

        #pragma unroll
        for (int c = 0; c < 4; ++c) {
            float4 wvc[GD2];
            #pragma unroll
            for (int dd = 0; dd < GD2; ++dd)
                wvc[dd] = ((const float4*)(Wm2 + (size_t)(d0 + dd) * DD))[lane + 64 * c];
            float4 h7[NN];
            #pragma unroll
            for (int j = 0; j < NN; ++j)
                h7[j] = ((const float4*)(h + (size_t)(b * NN + j) * DD))[lane + 64 * c];
            #pragma unroll
            for (int i = 0; i < NN; ++i) {
                float a0 = alC[wave][i][0], a1 = alC[wave][i][1],
                      a2 = alC[wave][i][2], a3 = alC[wave][i][3],
                      a4 = alC[wave][i][4], a5 = alC[wave][i][5],
                      a6 = alC[wave][i][6];
                float ax = a0 * h7[0].x + a1 * h7[1].x + a2 * h7[2].x +
                           a3 * h7[3].x + a4 * h7[4].x + a5 * h7[5].x +
                           a6 * h7[6].x;
                float ay = a0 * h7[0].y + a1 * h7[1].y + a2 * h7[2].y +
                           a3 * h7[3].y + a4 * h7[4].y + a5 * h7[5].y +
                           a6 * h7[6].y;
                float az = a0 * h7[0].z + a1 * h7[1].z + a2 * h7[2].z +
                           a3 * h7[3].z + a4 * h7[4].z + a5 * h7[5].z +
                           a6 * h7[6].z;
                float aw = a0 * h7[0].w + a1 * h7[1].w + a2 * h7[2].w +
                           a3 * h7[3].w + a4 * h7[4].w + a5 * h7[5].w +
                           a6 * h7[6].w;
                #pragma unroll
                for (int dd = 0; dd < GD2; ++dd) {
                    acc[i][dd] += ax * wvc[dd].x + ay * wvc[dd].y +
                                  az * wvc[dd].z + aw * wvc[dd].w;
                }
            }
        }

        #pragma unroll
        for (int i = 0; i < NN; ++i) {
            #pragma unroll
            for (int dd = 0; dd < GD2; ++dd) {
                float v = acc[i][dd];
                v += __shfl_xor(v, 1, 64);
                v += __shfl_xor(v, 2, 64);
                v += __shfl_xor(v, 4, 64);
                v += __shfl_xor(v, 8, 64);
                v += __shfl_xor(v, 16, 64);
                v += __shfl_xor(v, 32, 64);
                if (lane == 0)
                    on[(size_t)(b * NN + i) * DD + d0 + dd] = v;
            }
        }
    }
}

// ---------------------------------------------------------------------------
// K3: out[b,t,d] = x[b,t,d] + on[b, t%7, d].  grid = (TT, BB).  [R14 exact]
// ---------------------------------------------------------------------------
__global__ __launch_bounds__(256) void k_final(
    const float* __restrict__ x, const float* __restrict__ on,
    float* __restrict__ out) {
    int t = blockIdx.x;
    int b = blockIdx.y;
    int n = t % NN;
    size_t row4 = (size_t)(b * TT + t) * (DD / 4) + threadIdx.x;
    size_t on4 = (size_t)(b * NN + n) * (DD / 4) + threadIdx.x;
    float4 xv = ((const float4*)x)[row4];
    float4 ov = ((const float4*)on)[on4];
    nfloat4 r;
    r.x = xv.x + ov.x; r.y = xv.y + ov.y;
    r.z = xv.z + ov.z; r.w = xv.w + ov.w;
    __builtin_nontemporal_store(r, (nfloat4*)out + row4);
}

// ---------------------------------------------------------------------------
extern "C" void kernel_launch(void* const* d_in, const int* in_sizes, int n_in,
                              void* d_out, int out_size, void* d_ws, size_t ws_size,
                              hipStream_t stream) {
    const float* x     = (const float*)d_in[0];
    const float* W     = (const float*)d_in[1];
    const float* a_w   = (const float*)d_in[2];
    const float* out_W = (const float*)d_in[3];
    float* out = (float*)d_out;
    float* ws  = (float*)d_ws;

    // ws layout (floats)
    float* nodes = ws;                            // 56*1024
    float* h     = ws + 57344;                    // 56*1024
    float* on    = ws + 2 * 57344;                // 56*1024
    float* fpart = ws + 3 * 57344;                // 2*256*56 = 28672
    unsigned* done = (unsigned*)(ws + 3 * 57344 + 28672);

    k_mean<<<dim3(KS, BN), 512, 0, stream>>>(x, nodes, done);
    k_mid<<<dim3(NB1 + NB2), 512, 0, stream>>>(nodes, W, a_w, out_W,
                                               h, fpart, on, done);
    k_final<<<dim3(TT, BB), 256, 0, stream>>>(x, on, out);
}

// Round 16
// 299.890 us; speedup vs baseline: 3.9629x; 3.9629x over previous
//
#include <hip/hip_runtime.h>
#include <math.h>

#define BB 8
#define TT 4095
#define DD 1024
#define NN 7
#define GG 585           // TT / NN
#define BN (BB * NN)     // 56
#define GD 4             // gemv1: output columns per producer block
#define GD2 4            // attn+gemv2: output columns per consumer block
#define NB1 (DD / GD)    // 256 producer blocks
#define NB2 (DD / GD2)   // 256 consumer blocks
#define KS 8             // k_mean: k-slices of 32 float4 (512 B)

typedef float nfloat4 __attribute__((ext_vector_type(4)));

// ---------------------------------------------------------------------------
// K1: fused group-mean.  grid = (KS=8, BN), block = 512.  [R14 exact]
// Block (0,0) thread 0 also zeroes the k_mid handshake counter.
// ---------------------------------------------------------------------------
__global__ __launch_bounds__(512) void k_mean(
    const float* __restrict__ x, float* __restrict__ nodes,
    unsigned* __restrict__ done) {
    if (blockIdx.x == 0 && blockIdx.y == 0 && threadIdx.x == 0) *done = 0u;

    int ks = blockIdx.x;             // 0..7 (32-float4 slice of D)
    int bn = blockIdx.y;             // 0..55
    int b = bn / NN, n = bn % NN;
    int t = threadIdx.x;
    int gi = t >> 5;                 // 0..15 g-partition
    int kg = t & 31;                 // 0..31 f4 within slice

    const float4* xp = (const float4*)(x + (size_t)(b * TT + n) * DD) +
                       ks * 32 + kg;
    float ax = 0.f, ay = 0.f, az = 0.f, aw = 0.f;
    #pragma unroll 4
    for (int g = gi; g < GG; g += 16) {
        float4 v = xp[(size_t)g * NN * (DD / 4)];
        ax += v.x; ay += v.y; az += v.z; aw += v.w;
    }

    __shared__ float4 red[16][32];   // [gi][kg], 8 KB
    float4 r; r.x = ax; r.y = ay; r.z = az; r.w = aw;
    red[gi][kg] = r;
    __syncthreads();

    if (t < 32) {                    // kg = t
        float4 a = red[0][t];
        #pragma unroll
        for (int g2 = 1; g2 < 16; ++g2) {
            float4 v = red[g2][t];
            a.x += v.x; a.y += v.y; a.z += v.z; a.w += v.w;
        }
        const float sc = 1.0f / (float)GG;
        a.x *= sc; a.y *= sc; a.z *= sc; a.w *= sc;
        ((float4*)(nodes + (size_t)bn * DD))[ks * 32 + t] = a;
    }
}

// ---------------------------------------------------------------------------
// K2: merged middle kernel.  grid = NB1 + NB2 = 512, block = 512.
// Blocks [0, NB1): gemv_f producer (h, fpart), then release-add `done`.
// Blocks [NB1, 512): ONE thread polls `done` (s_sleep between probes) until
// == NB1, then __syncthreads releases the block into attn+gemv2.
// R15 lesson: all-thread spin on one agent-scope address = fabric storm
// (214 MB fetch, 12x slowdown).  Poll topology, not scope, was the bug.
// __launch_bounds__(512,4): VGPR<=128 -> all 512 blocks co-resident.
// ---------------------------------------------------------------------------
__global__ __launch_bounds__(512, 4) void k_mid(
    const float* __restrict__ A, const float* __restrict__ Wm1,
    const float* __restrict__ a_w, const float* __restrict__ Wm2,
    float* __restrict__ h, float* __restrict__ fpart,
    float* __restrict__ on, unsigned* __restrict__ done) {
    int t = threadIdx.x;
    int wave = t >> 6, lane = t & 63;

    if (blockIdx.x < NB1) {
        // ---------------- producer: h = A @ Wm1^T + f-partials ----------------
        int d0 = blockIdx.x * GD;

        float4 wv[GD][4];
        #pragma unroll
        for (int dd = 0; dd < GD; ++dd) {
            const float4* wp = (const float4*)(Wm1 + (size_t)(d0 + dd) * DD);
            #pragma unroll
            for (int kk = 0; kk < 4; ++kk) wv[dd][kk] = wp[lane + 64 * kk];
        }

        const float4* ap = (const float4*)A + (size_t)(wave * 7) * (DD / 4);
        float acc[7][GD];
        #pragma unroll
        for (int i = 0; i < 7; ++i) {
            const float4* ar = ap + (size_t)i * (DD / 4);
            float4 a0 = ar[lane];
            float4 a1 = ar[lane + 64];
            float4 a2 = ar[lane + 128];
            float4 a3 = ar[lane + 192];
            #pragma unroll
            for (int dd = 0; dd < GD; ++dd) {
                float v = a0.x * wv[dd][0].x + a0.y * wv[dd][0].y +
                          a0.z * wv[dd][0].z + a0.w * wv[dd][0].w;
                v += a1.x * wv[dd][1].x + a1.y * wv[dd][1].y +
                     a1.z * wv[dd][1].z + a1.w * wv[dd][1].w;
                v += a2.x * wv[dd][2].x + a2.y * wv[dd][2].y +
                     a2.z * wv[dd][2].z + a2.w * wv[dd][2].w;
                v += a3.x * wv[dd][3].x + a3.y * wv[dd][3].y +
                     a3.z * wv[dd][3].z + a3.w * wv[dd][3].w;
                acc[i][dd] = v;
            }
        }

        float a1v[GD], a2v[GD];
        #pragma unroll
        for (int dd = 0; dd < GD; ++dd) {
            a1v[dd] = a_w[d0 + dd];
            a2v[dd] = a_w[DD + d0 + dd];
        }

        #pragma unroll
        for (int i = 0; i < 7; ++i) {
            float f1i = 0.f, f2i = 0.f;
            #pragma unroll
            for (int dd = 0; dd < GD; ++dd) {
                float v = acc[i][dd];
                v += __shfl_xor(v, 1, 64);
                v += __shfl_xor(v, 2, 64);
                v += __shfl_xor(v, 4, 64);
                v += __shfl_xor(v, 8, 64);
                v += __shfl_xor(v, 16, 64);
                v += __shfl_xor(v, 32, 64);
                f1i += v * a1v[dd];
                f2i += v * a2v[dd];
                if (lane == 0) h[(size_t)(wave * 7 + i) * DD + d0 + dd] = v;
            }
            if (lane == 0) {
                int row = wave * 7 + i;
                fpart[(size_t)blockIdx.x * BN + row] = f1i;
                fpart[(size_t)(NB1 + blockIdx.x) * BN + row] = f2i;
            }
        }

        __syncthreads();             // all block stores issued
        if (t == 0) {
            __threadfence();         // agent fence: L2 writeback
            __hip_atomic_fetch_add(done, 1u, __ATOMIC_RELEASE,
                                   __HIP_MEMORY_SCOPE_AGENT);
        }
    } else {
        // ---------------- consumer: attention + on = s @ Wm2^T ----------------
        int d0 = (blockIdx.x - NB1) * GD2;

        // single-thread poll; ~0.4 us s_sleep between probes; bounded so a
        // handshake bug becomes a validation failure, not a hang.
        if (t == 0) {
            long it = 0;
            while (__hip_atomic_load(done, __ATOMIC_ACQUIRE,
                                     __HIP_MEMORY_SCOPE_AGENT) < (unsigned)NB1) {
                __builtin_amdgcn_s_sleep(16);
                if (++it > (1L << 20)) break;
            }
        }
        __syncthreads();

        __shared__ float f[2][BN];
        __shared__ float alC[8][NN][NN];

        if (t < 2 * BN) {
            int sel = t / BN, row = t - sel * BN;
            const float* fp = fpart + (size_t)sel * NB1 * BN + row;
            float s0 = 0.f, s1 = 0.f, s2 = 0.f, s3 = 0.f;
            #pragma unroll 4
            for (int blk = 0; blk < NB1; blk += 4) {
                s0 += fp[(size_t)blk * BN];
                s1 += fp[(size_t)(blk + 1) * BN];
                s2 += fp[(size_t)(blk + 2) * BN];
                s3 += fp[(size_t)(blk + 3) * BN];
            }
            f[sel][row] = (s0 + s1) + (s2 + s3);
        }
        __syncthreads();

        int b = wave;                // one batch per wave
        if (lane < NN) {
            int i = lane;
            unsigned m = (i == 0) ? 0x7Eu
                : (1u | (1u << (i % 6 + 1)) | (1u << ((i + 4) % 6 + 1)));
            float f1 = f[0][b * NN + i];
            float mx = -1e30f;
            #pragma unroll
            for (int j = 0; j < NN; ++j)
                if ((m >> j) & 1u) mx = fmaxf(mx, f1 + f[1][b * NN + j]);
            float ssum = 0.f;
            float ex[NN];
            #pragma unroll
            for (int j = 0; j < NN; ++j) {
                ex[j] = ((m >> j) & 1u) ? __expf(f1 + f[1][b * NN + j] - mx) : 0.f;
                ssum += ex[j];
            }
            float inv = 1.0f / ssum;
            #pragma unroll
            for (int j = 0; j < NN; ++j) alC[wave][i][j] = ex[j] * inv;
        }
        __syncthreads();

        float acc[NN][GD2];
        #pragma unroll
        for (int i = 0; i < NN; ++i)
            #pragma unroll
            for (int dd = 0; dd < GD2; ++dd) acc[i][dd] = 0.f;

        #pragma unroll
        for (int c = 0; c < 4; ++c) {
            float4 wvc[GD2];
            #pragma unroll
            for (int dd = 0; dd < GD2; ++dd)
                wvc[dd] = ((const float4*)(Wm2 + (size_t)(d0 + dd) * DD))[lane + 64 * c];
            float4 h7[NN];
            #pragma unroll
            for (int j = 0; j < NN; ++j)
                h7[j] = ((const float4*)(h + (size_t)(b * NN + j) * DD))[lane + 64 * c];
            #pragma unroll
            for (int i = 0; i < NN; ++i) {
                float a0 = alC[wave][i][0], a1 = alC[wave][i][1],
                      a2 = alC[wave][i][2], a3 = alC[wave][i][3],
                      a4 = alC[wave][i][4], a5 = alC[wave][i][5],
                      a6 = alC[wave][i][6];
                float ax = a0 * h7[0].x + a1 * h7[1].x + a2 * h7[2].x +
                           a3 * h7[3].x + a4 * h7[4].x + a5 * h7[5].x +
                           a6 * h7[6].x;
                float ay = a0 * h7[0].y + a1 * h7[1].y + a2 * h7[2].y +
                           a3 * h7[3].y + a4 * h7[4].y + a5 * h7[5].y +
                           a6 * h7[6].y;
                float az = a0 * h7[0].z + a1 * h7[1].z + a2 * h7[2].z +
                           a3 * h7[3].z + a4 * h7[4].z + a5 * h7[5].z +
                           a6 * h7[6].z;
                float aw = a0 * h7[0].w + a1 * h7[1].w + a2 * h7[2].w +
                           a3 * h7[3].w + a4 * h7[4].w + a5 * h7[5].w +
                           a6 * h7[6].w;
                #pragma unroll
                for (int dd = 0; dd < GD2; ++dd) {
                    acc[i][dd] += ax * wvc[dd].x + ay * wvc[dd].y +
                                  az * wvc[dd].z + aw * wvc[dd].w;
                }
            }
        }

        #pragma unroll
        for (int i = 0; i < NN; ++i) {
            #pragma unroll
            for (int dd = 0; dd < GD2; ++dd) {
                float v = acc[i][dd];
                v += __shfl_xor(v, 1, 64);
                v += __shfl_xor(v, 2, 64);
                v += __shfl_xor(v, 4, 64);
                v += __shfl_xor(v, 8, 64);
                v += __shfl_xor(v, 16, 64);
                v += __shfl_xor(v, 32, 64);
                if (lane == 0)
                    on[(size_t)(b * NN + i) * DD + d0 + dd] = v;
            }
        }
    }
}

// ---------------------------------------------------------------------------
// K3: out[b,t,d] = x[b,t,d] + on[b, t%7, d].  grid = (TT, BB).  [R14 exact]
// ---------------------------------------------------------------------------
__global__ __launch_bounds__(256) void k_final(
    const float* __restrict__ x, const float* __restrict__ on,
    float* __restrict__ out) {
    int t = blockIdx.x;
    int b = blockIdx.y;
    int n = t % NN;
    size_t row4 = (size_t)(b * TT + t) * (DD / 4) + threadIdx.x;
    size_t on4 = (size_t)(b * NN + n) * (DD / 4) + threadIdx.x;
    float4 xv = ((const float4*)x)[row4];
    float4 ov = ((const float4*)on)[on4];
    nfloat4 r;
    r.x = xv.x + ov.x; r.y = xv.y + ov.y;
    r.z = xv.z + ov.z; r.w = xv.w + ov.w;
    __builtin_nontemporal_store(r, (nfloat4*)out + row4);
}

// ---------------------------------------------------------------------------
extern "C" void kernel_launch(void* const* d_in, const int* in_sizes, int n_in,
                              void* d_out, int out_size, void* d_ws, size_t ws_size,
                              hipStream_t stream) {
    const float* x     = (const float*)d_in[0];
    const float* W     = (const float*)d_in[1];
    const float* a_w   = (const float*)d_in[2];
    const float* out_W = (const float*)d_in[3];
    float* out = (float*)d_out;
    float* ws  = (float*)d_ws;

    // ws layout (floats)
    float* nodes = ws;                            // 56*1024
    float* h     = ws + 57344;                    // 56*1024
    float* on    = ws + 2 * 57344;                // 56*1024
    float* fpart = ws + 3 * 57344;                // 2*256*56 = 28672
    unsigned* done = (unsigned*)(ws + 3 * 57344 + 28672);

    k_mean<<<dim3(KS, BN), 512, 0, stream>>>(x, nodes, done);
    k_mid<<<dim3(NB1 + NB2), 512, 0, stream>>>(nodes, W, a_w, out_W,
                                               h, fpart, on, done);
    k_final<<<dim3(TT, BB), 256, 0, stream>>>(x, on, out);
}

// Round 17
// 92.706 us; speedup vs baseline: 12.8194x; 3.2349x over previous
//
#include <hip/hip_runtime.h>
#include <math.h>

#define BB 8
#define TT 4095
#define DD 1024
#define NN 7
#define GG 585           // TT / NN
#define BN (BB * NN)     // 56
#define GD 4             // gemv1: output columns per block
#define GD2 4            // attn+gemv2: output columns per block
#define NB1 (DD / GD)    // 256 gemv1 blocks (also f-partial count)
#define KS 8             // k_mean: k-slices of 32 float4 (512 B)

typedef float nfloat4 __attribute__((ext_vector_type(4)));

// ---------------------------------------------------------------------------
// K1: fused group-mean.  grid = (KS=8, BN) = 448 blocks, block = 512.
// Slice = 32 float4 = 512 B contiguous per 32-lane group.
// ---------------------------------------------------------------------------
__global__ __launch_bounds__(512) void k_mean(
    const float* __restrict__ x, float* __restrict__ nodes) {
    int ks = blockIdx.x;             // 0..7 (32-float4 slice of D)
    int bn = blockIdx.y;             // 0..55
    int b = bn / NN, n = bn % NN;
    int t = threadIdx.x;
    int gi = t >> 5;                 // 0..15 g-partition
    int kg = t & 31;                 // 0..31 f4 within slice

    const float4* xp = (const float4*)(x + (size_t)(b * TT + n) * DD) +
                       ks * 32 + kg;
    float ax = 0.f, ay = 0.f, az = 0.f, aw = 0.f;
    #pragma unroll 4
    for (int g = gi; g < GG; g += 16) {
        float4 v = xp[(size_t)g * NN * (DD / 4)];
        ax += v.x; ay += v.y; az += v.z; aw += v.w;
    }

    __shared__ float4 red[16][32];   // [gi][kg], 8 KB
    float4 r; r.x = ax; r.y = ay; r.z = az; r.w = aw;
    red[gi][kg] = r;
    __syncthreads();

    if (t < 32) {                    // kg = t
        float4 a = red[0][t];
        #pragma unroll
        for (int g2 = 1; g2 < 16; ++g2) {
            float4 v = red[g2][t];
            a.x += v.x; a.y += v.y; a.z += v.z; a.w += v.w;
        }
        const float sc = 1.0f / (float)GG;
        a.x *= sc; a.y *= sc; a.z *= sc; a.w *= sc;
        ((float4*)(nodes + (size_t)bn * DD))[ks * 32 + t] = a;
    }
}

// ---------------------------------------------------------------------------
// K2: h = nodes @ W^T + per-block f-partials.  grid = NB1, block = 512.
// ---------------------------------------------------------------------------
__global__ __launch_bounds__(512) void k_gemv_f(
    const float* __restrict__ A, const float* __restrict__ Wm,
    const float* __restrict__ a_w,
    float* __restrict__ Cout, float* __restrict__ fpart) {
    int d0 = blockIdx.x * GD;
    int t = threadIdx.x;
    int wave = t >> 6, lane = t & 63;

    float4 wv[GD][4];
    #pragma unroll
    for (int dd = 0; dd < GD; ++dd) {
        const float4* wp = (const float4*)(Wm + (size_t)(d0 + dd) * DD);
        #pragma unroll
        for (int kk = 0; kk < 4; ++kk) wv[dd][kk] = wp[lane + 64 * kk];
    }

    const float4* ap = (const float4*)A + (size_t)(wave * 7) * (DD / 4);
    float acc[7][GD];
    #pragma unroll
    for (int i = 0; i < 7; ++i) {
        const float4* ar = ap + (size_t)i * (DD / 4);
        float4 a0 = ar[lane];
        float4 a1 = ar[lane + 64];
        float4 a2 = ar[lane + 128];
        float4 a3 = ar[lane + 192];
        #pragma unroll
        for (int dd = 0; dd < GD; ++dd) {
            float v = a0.x * wv[dd][0].x + a0.y * wv[dd][0].y +
                      a0.z * wv[dd][0].z + a0.w * wv[dd][0].w;
            v += a1.x * wv[dd][1].x + a1.y * wv[dd][1].y +
                 a1.z * wv[dd][1].z + a1.w * wv[dd][1].w;
            v += a2.x * wv[dd][2].x + a2.y * wv[dd][2].y +
                 a2.z * wv[dd][2].z + a2.w * wv[dd][2].w;
            v += a3.x * wv[dd][3].x + a3.y * wv[dd][3].y +
                 a3.z * wv[dd][3].z + a3.w * wv[dd][3].w;
            acc[i][dd] = v;
        }
    }

    float a1v[GD], a2v[GD];
    #pragma unroll
    for (int dd = 0; dd < GD; ++dd) {
        a1v[dd] = a_w[d0 + dd];
        a2v[dd] = a_w[DD + d0 + dd];
    }

    #pragma unroll
    for (int i = 0; i < 7; ++i) {
        float f1i = 0.f, f2i = 0.f;
        #pragma unroll
        for (int dd = 0; dd < GD; ++dd) {
            float v = acc[i][dd];
            v += __shfl_xor(v, 1, 64);
            v += __shfl_xor(v, 2, 64);
            v += __shfl_xor(v, 4, 64);
            v += __shfl_xor(v, 8, 64);
            v += __shfl_xor(v, 16, 64);
            v += __shfl_xor(v, 32, 64);
            f1i += v * a1v[dd];
            f2i += v * a2v[dd];
            if (lane == 0) Cout[(size_t)(wave * 7 + i) * DD + d0 + dd] = v;
        }
        if (lane == 0) {
            int row = wave * 7 + i;
            fpart[(size_t)blockIdx.x * BN + row] = f1i;
            fpart[(size_t)(NB1 + blockIdx.x) * BN + row] = f2i;
        }
    }
}

// ---------------------------------------------------------------------------
// K3: fused attention + gemv2.  grid = DD/GD2 = 256, block = 512.
// ---------------------------------------------------------------------------
__global__ __launch_bounds__(512) void k_attn_gemv(
    const float* __restrict__ h, const float* __restrict__ fpart,
    const float* __restrict__ Wm, float* __restrict__ Cout) {
    int d0 = blockIdx.x * GD2;
    int t = threadIdx.x;
    int wave = t >> 6, lane = t & 63;

    __shared__ float f[2][BN];

    if (t < 2 * BN) {
        int sel = t / BN, row = t - sel * BN;
        const float* fp = fpart + (size_t)sel * NB1 * BN + row;
        float s0 = 0.f, s1 = 0.f, s2 = 0.f, s3 = 0.f;
        #pragma unroll 4
        for (int blk = 0; blk < NB1; blk += 4) {
            s0 += fp[(size_t)blk * BN];
            s1 += fp[(size_t)(blk + 1) * BN];
            s2 += fp[(size_t)(blk + 2) * BN];
            s3 += fp[(size_t)(blk + 3) * BN];
        }
        f[sel][row] = (s0 + s1) + (s2 + s3);
    }
    __syncthreads();

    const unsigned msk[NN] = {0x7Eu, 0x45u, 0x0Bu, 0x15u, 0x29u, 0x51u, 0x23u};
    int b = wave;                    // one batch per wave

    float alpha[NN][NN];
    #pragma unroll
    for (int i = 0; i < NN; ++i) {
        float f1 = f[0][b * NN + i];
        float m = -1e30f;
        #pragma unroll
        for (int j = 0; j < NN; ++j)
            if ((msk[i] >> j) & 1u) m = fmaxf(m, f1 + f[1][b * NN + j]);
        float ssum = 0.f;
        #pragma unroll
        for (int j = 0; j < NN; ++j) {
            float e = ((msk[i] >> j) & 1u) ? __expf(f1 + f[1][b * NN + j] - m) : 0.f;
            alpha[i][j] = e;
            ssum += e;
        }
        float inv = 1.0f / ssum;
        #pragma unroll
        for (int j = 0; j < NN; ++j) alpha[i][j] *= inv;
    }

    float acc[NN][GD2];
    #pragma unroll
    for (int i = 0; i < NN; ++i)
        #pragma unroll
        for (int dd = 0; dd < GD2; ++dd) acc[i][dd] = 0.f;

    #pragma unroll
    for (int c = 0; c < 4; ++c) {
        float4 wvc[GD2];
        #pragma unroll
        for (int dd = 0; dd < GD2; ++dd)
            wvc[dd] = ((const float4*)(Wm + (size_t)(d0 + dd) * DD))[lane + 64 * c];
        float4 h7[NN];
        #pragma unroll
        for (int j = 0; j < NN; ++j)
            h7[j] = ((const float4*)(h + (size_t)(b * NN + j) * DD))[lane + 64 * c];
        #pragma unroll
        for (int i = 0; i < NN; ++i) {
            float ax = 0.f, ay = 0.f, az = 0.f, aw = 0.f;
            #pragma unroll
            for (int j = 0; j < NN; ++j) {
                float a = alpha[i][j];
                ax += a * h7[j].x; ay += a * h7[j].y;
                az += a * h7[j].z; aw += a * h7[j].w;
            }
            #pragma unroll
            for (int dd = 0; dd < GD2; ++dd) {
                acc[i][dd] += ax * wvc[dd].x + ay * wvc[dd].y +
                              az * wvc[dd].z + aw * wvc[dd].w;
            }
        }
    }

    #pragma unroll
    for (int i = 0; i < NN; ++i) {
        #pragma unroll
        for (int dd = 0; dd < GD2; ++dd) {
            float v = acc[i][dd];
            v += __shfl_xor(v, 1, 64);
            v += __shfl_xor(v, 2, 64);
            v += __shfl_xor(v, 4, 64);
            v += __shfl_xor(v, 8, 64);
            v += __shfl_xor(v, 16, 64);
            v += __shfl_xor(v, 32, 64);
            if (lane == 0)
                Cout[(size_t)(b * NN + i) * DD + d0 + dd] = v;
        }
    }
}

// ---------------------------------------------------------------------------
// K4: out[b,t,d] = x[b,t,d] + on[b, t%7, d].  grid = (TT, BB).  nt-store.
// ---------------------------------------------------------------------------
__global__ __launch_bounds__(256) void k_final(
    const float* __restrict__ x, const float* __restrict__ on,
    float* __restrict__ out) {
    int t = blockIdx.x;
    int b = blockIdx.y;
    int n = t % NN;
    size_t row4 = (size_t)(b * TT + t) * (DD / 4) + threadIdx.x;
    size_t on4 = (size_t)(b * NN + n) * (DD / 4) + threadIdx.x;
    float4 xv = ((const float4*)x)[row4];
    float4 ov = ((const float4*)on)[on4];
    nfloat4 r;
    r.x = xv.x + ov.x; r.y = xv.y + ov.y;
    r.z = xv.z + ov.z; r.w = xv.w + ov.w;
    __builtin_nontemporal_store(r, (nfloat4*)out + row4);
}

// ---------------------------------------------------------------------------
extern "C" void kernel_launch(void* const* d_in, const int* in_sizes, int n_in,
                              void* d_out, int out_size, void* d_ws, size_t ws_size,
                              hipStream_t stream) {
    const float* x     = (const float*)d_in[0];
    const float* W     = (const float*)d_in[1];
    const float* a_w   = (const float*)d_in[2];
    const float* out_W = (const float*)d_in[3];
    float* out = (float*)d_out;
    float* ws  = (float*)d_ws;

    // ws layout (floats)
    float* nodes = ws;                       // 56*1024
    float* h     = ws + 57344;               // 56*1024
    float* on    = ws + 2 * 57344;           // 56*1024
    float* fpart = ws + 3 * 57344;           // 2*256*56 = 28672

    k_mean<<<dim3(KS, BN), 512, 0, stream>>>(x, nodes);
    k_gemv_f<<<dim3(NB1), 512, 0, stream>>>(nodes, W, a_w, h, fpart);
    k_attn_gemv<<<dim3(DD / GD2), 512, 0, stream>>>(h, fpart, out_W, on);
    k_final<<<dim3(TT, BB), 256, 0, stream>>>(x, on, out);
}